// Round 9
// baseline (540.224 us; speedup 1.0000x reference)
//
#include <hip/hip_runtime.h>

typedef unsigned short u16;
typedef short bf16x8 __attribute__((ext_vector_type(8)));
typedef float f32x4 __attribute__((ext_vector_type(4)));
typedef float f32x16 __attribute__((ext_vector_type(16)));
typedef unsigned short u16x8 __attribute__((ext_vector_type(8)));

#define GLOBAL_AS __attribute__((address_space(1)))
#define LDS_AS __attribute__((address_space(3)))
#define DEVINL __device__ __forceinline__

#define BATCH 2
#define TSEQ 2048
#define NHEAD 16
#define QK 192
#define VD 128
#define HID 2048
#define MROWS 4096
#define SCALE_QK 0.07216878364870323f   // 192^-0.5

DEVINL float b2f(u16 u) { union { unsigned i; float f; } x; x.i = ((unsigned)u) << 16; return x.f; }
DEVINL u16 f2b(float f) {
    union { float f; unsigned u; } x; x.f = f;
    unsigned r = x.u + 0x7fffu + ((x.u >> 16) & 1u);
    return (u16)(r >> 16);
}
DEVINL void gload_lds16(const u16* g, u16* l) {
    __builtin_amdgcn_global_load_lds((const GLOBAL_AS unsigned*)g, (LDS_AS unsigned*)l, 16, 0, 0);
}
DEVINL unsigned pk2(float a, float b) {
    unsigned d;
    asm("v_cvt_pk_bf16_f32 %0, %1, %2" : "=v"(d) : "v"(a), "v"(b));
    return d;
}

// ---------------- conversion kernels ----------------

__global__ void cvt_bf16x8(const float* __restrict__ in, u16* __restrict__ out, int n8) {
    int i = blockIdx.x * 256 + threadIdx.x;
    if (i < n8) {
        const float4* p = (const float4*)(in + (size_t)i * 8);
        float4 x = p[0], y = p[1];
        u16x8 o;
        o[0] = f2b(x.x); o[1] = f2b(x.y); o[2] = f2b(x.z); o[3] = f2b(x.w);
        o[4] = f2b(y.x); o[5] = f2b(y.y); o[6] = f2b(y.z); o[7] = f2b(y.w);
        *(u16x8*)(out + (size_t)i * 8) = o;
    }
}

__global__ void rope_tab_k(const float* __restrict__ freqs, float2* __restrict__ tab) {
    int i = blockIdx.x * 256 + threadIdx.x;   // 65536 = 2048*32
    float f = freqs[i], s, c;
    sincosf(f, &s, &c);
    tab[i] = make_float2(c, s);
}

// in: f32 [R][C] row-major -> out: bf16 [Cpad][R], zeros for c >= C
__global__ void transpose_cvt(const float* __restrict__ in, u16* __restrict__ out,
                              int R, int C, int Cpad) {
    __shared__ float tile[32][33];
    int c0 = blockIdx.x * 32, r0 = blockIdx.y * 32;
    int tx = threadIdx.x, ty = threadIdx.y;   // 32 x 8
#pragma unroll
    for (int j = 0; j < 4; j++) {
        int r = r0 + ty + j * 8, c = c0 + tx;
        tile[ty + j * 8][tx] = (c < C) ? in[(size_t)r * C + c] : 0.f;
    }
    __syncthreads();
#pragma unroll
    for (int j = 0; j < 4; j++) {
        int oc = c0 + ty + j * 8;
        int orr = r0 + tx;
        if (oc < Cpad) out[(size_t)oc * R + orr] = f2b(tile[tx][ty + j * 8]);
    }
}

// ---------------- GEMM: C = A[M][K] * BT[N][K]^T ----------------
// MODE 0: q epilogue (fused RoPE via tab) -> qbuf bf16 (b,h,t,192)
// MODE 1: kv f32 -> [row][640]
// MODE 2: kvb -> k_nope into kbuf + v into vbuf AND vtbuf (out2)
// MODE 3: f32 out [row][2048]
template<int MODE>
__global__ __launch_bounds__(256)
void gemm_bt(const u16* __restrict__ A, const u16* __restrict__ BT, int Kdim,
             void* __restrict__ out0, void* __restrict__ out1, void* __restrict__ out2,
             const float2* __restrict__ tab) {
    __shared__ __align__(16) u16 As[128 * 32];
    __shared__ __align__(16) u16 Bs[128 * 32];
    const int tid = threadIdx.x, lane = tid & 63, wave = tid >> 6;
    const int m0 = blockIdx.x * 128, n0 = blockIdx.y * 128;
    const int wr = wave >> 1, wc = wave & 1;

    f32x4 acc[4][4];
#pragma unroll
    for (int i = 0; i < 4; i++)
#pragma unroll
        for (int j = 0; j < 4; j++) acc[i][j] = f32x4{0.f, 0.f, 0.f, 0.f};

    const int e0 = (wave * 2 + 0) * 512 + lane * 8;
    const int e1 = (wave * 2 + 1) * 512 + lane * 8;
    const u16* gA0 = A + (size_t)(m0 + (e0 >> 5)) * Kdim + (e0 & 31);
    const u16* gA1 = A + (size_t)(m0 + (e1 >> 5)) * Kdim + (e1 & 31);
    const u16* gB0 = BT + (size_t)(n0 + (e0 >> 5)) * Kdim + (e0 & 31);
    const u16* gB1 = BT + (size_t)(n0 + (e1 >> 5)) * Kdim + (e1 & 31);
    u16* lA0 = &As[(wave * 2 + 0) * 512];
    u16* lA1 = &As[(wave * 2 + 1) * 512];
    u16* lB0 = &Bs[(wave * 2 + 0) * 512];
    u16* lB1 = &Bs[(wave * 2 + 1) * 512];

    const int arow = lane & 15, koff = (lane >> 4) * 8;

    for (int k0 = 0; k0 < Kdim; k0 += 32) {
        gload_lds16(gA0, lA0); gload_lds16(gA1, lA1);
        gload_lds16(gB0, lB0); gload_lds16(gB1, lB1);
        gA0 += 32; gA1 += 32; gB0 += 32; gB1 += 32;
        asm volatile("s_waitcnt vmcnt(0)" ::: "memory");
        __syncthreads();
        bf16x8 af[4], bfr[4];
#pragma unroll
        for (int i = 0; i < 4; i++)
            af[i] = *(const bf16x8*)&As[(wr * 64 + i * 16 + arow) * 32 + koff];
#pragma unroll
        for (int j = 0; j < 4; j++)
            bfr[j] = *(const bf16x8*)&Bs[(wc * 64 + j * 16 + arow) * 32 + koff];
#pragma unroll
        for (int i = 0; i < 4; i++)
#pragma unroll
            for (int j = 0; j < 4; j++)
                acc[i][j] = __builtin_amdgcn_mfma_f32_16x16x32_bf16(af[i], bfr[j], acc[i][j], 0, 0, 0);
        __syncthreads();
    }

#pragma unroll
    for (int i = 0; i < 4; i++)
#pragma unroll
        for (int j = 0; j < 4; j++)
#pragma unroll
            for (int r = 0; r < 4; r++) {
                int row = m0 + wr * 64 + i * 16 + (lane >> 4) * 4 + r;
                int col = n0 + wc * 64 + j * 16 + (lane & 15);
                float v = acc[i][j][r];
                if constexpr (MODE == 0) {
                    int h = col / 192, d = col % 192;
                    int b = row >> 11, t = row & 2047;
                    float vv = v;
                    float pv = __shfl_xor(v, 1);   // RoPE partner (same row, col^1)
                    if (d >= 128) {
                        float2 cs = tab[t * 32 + ((d - 128) >> 1)];
                        vv = v * cs.x + pv * ((lane & 1) ? cs.y : -cs.y);
                    }
                    ((u16*)out0)[((size_t)(b * 16 + h) * 2048 + t) * 192 + d] = f2b(vv);
                } else if constexpr (MODE == 1) {
                    ((float*)out0)[(size_t)row * 640 + col] = v;
                } else if constexpr (MODE == 2) {
                    int h = col >> 8, d = col & 255;
                    int b = row >> 11, t = row & 2047;
                    size_t base = (size_t)(b * 16 + h) * 2048 + t;
                    if (d < 128) ((u16*)out0)[base * 192 + d] = f2b(v);
                    else {
                        u16 bv = f2b(v);
                        ((u16*)out1)[base * 128 + (d - 128)] = bv;
                        ((u16*)out2)[((size_t)(b * 16 + h) * 128 + (d - 128)) * 2048 + t] = bv;
                    }
                } else {
                    ((float*)out0)[(size_t)row * 2048 + col] = v;
                }
            }
}

// ---------------- LayerNorm(512) + k_rope broadcast ----------------
__global__ __launch_bounds__(256)
void ln_krope(const float* __restrict__ kvf, const float* __restrict__ gamma,
              const float* __restrict__ beta, const float2* __restrict__ tab,
              u16* __restrict__ kvlat, u16* __restrict__ kbuf) {
    int row = blockIdx.x, tid = threadIdx.x;
    const float* x = kvf + (size_t)row * 640;
    float v0 = x[tid], v1 = x[tid + 256];
    float s = v0 + v1, sq = v0 * v0 + v1 * v1;
#pragma unroll
    for (int off = 1; off < 64; off <<= 1) { s += __shfl_xor(s, off); sq += __shfl_xor(sq, off); }
    __shared__ float ssum[4], ssq[4];
    if ((tid & 63) == 0) { ssum[tid >> 6] = s; ssq[tid >> 6] = sq; }
    __syncthreads();
    s = ssum[0] + ssum[1] + ssum[2] + ssum[3];
    sq = ssq[0] + ssq[1] + ssq[2] + ssq[3];
    float mu = s * (1.f / 512.f);
    float var = sq * (1.f / 512.f) - mu * mu;
    float rs = rsqrtf(var + 1e-5f);
    kvlat[(size_t)row * 512 + tid] = f2b((v0 - mu) * rs * gamma[tid] + beta[tid]);
    kvlat[(size_t)row * 512 + tid + 256] = f2b((v1 - mu) * rs * gamma[tid + 256] + beta[tid + 256]);
    if (tid < 32) {
        int t = row & 2047, b = row >> 11;
        float x1 = x[512 + 2 * tid], x2 = x[512 + 2 * tid + 1];
        float2 cs = tab[t * 32 + tid];
        u16 u1 = f2b(x1 * cs.x - x2 * cs.y), u2 = f2b(x1 * cs.y + x2 * cs.x);
        for (int h = 0; h < 16; ++h) {
            size_t base = ((size_t)(b * 16 + h) * 2048 + t) * 192 + 128 + 2 * tid;
            kbuf[base] = u1; kbuf[base + 1] = u2;
        }
    }
}

// ---------------- parallel suffix scan of V -> u term written into attnb ----------------
__global__ void suff1(const u16* __restrict__ vbuf, float* __restrict__ psum) {
    int bh = blockIdx.x, c = blockIdx.y, d = threadIdx.x;   // 128 threads
    float s = 0.f;
    const u16* vp = vbuf + ((size_t)bh * 2048 + c * 128) * 128 + d;
    for (int tt = 0; tt < 128; ++tt) s += b2f(vp[(size_t)tt * 128]);
    psum[((size_t)bh * 16 + c) * 128 + d] = s;
}
__global__ void suff2(const float* __restrict__ psum, float* __restrict__ csuf) {
    int bh = blockIdx.x, d = threadIdx.x;
    float run = 0.f;
    for (int c = 15; c >= 0; --c) {
        csuf[((size_t)bh * 16 + c) * 128 + d] = run;
        run += psum[((size_t)bh * 16 + c) * 128 + d];
    }
}
__global__ void suff3(const u16* __restrict__ vbuf, const float* __restrict__ csuf,
                      u16* __restrict__ attnb) {
    int bh = blockIdx.x, c = blockIdx.y, d = threadIdx.x;
    int b = bh >> 4, h = bh & 15;
    float run = csuf[((size_t)bh * 16 + c) * 128 + d];
    for (int tt = 127; tt >= 0; --tt) {
        int t = c * 128 + tt;
        attnb[((size_t)b * 2048 + t) * 2048 + h * 128 + d] = f2b(run * 0.0625f);
        run += b2f(vbuf[((size_t)bh * 2048 + t) * 128 + d]);
    }
}

// ---------------- Z kernel: zbufT[b][s][t] = 1 / sum_h exp(SCALE*q.k), bf16 ----------------
// swapped 32x32 MFMA; single-buffered Q regs + dbuf K LDS; XCD-chunked triangle map
__global__ __launch_bounds__(256, 3)
void z_kernel(const u16* __restrict__ qbuf, const u16* __restrict__ kbuf,
              u16* __restrict__ zbufT) {
    __shared__ __align__(16) u16 Ks[2 * 12288];
    const int tid = threadIdx.x, lane = tid & 63, wave = tid >> 6;
    const int hi = lane >> 5, l31 = lane & 31;
    const int tgrp = wave & 1, sblk = wave >> 1;
    int id = blockIdx.x;            // 0..1055
    // T1 XCD-chunked map: HW round-robins id%8 across XCDs. Same-XCD blocks get a
    // contiguous triangle chunk with the same b -> Q/K tiles become L2-resident.
    int b = id & 1;                 // XCD parity picks batch
    int q4 = (id >> 1) & 3;         // quarter chunk within this b
    int j = id >> 3;                // 0..131 position within chunk
    int p = q4 * 132 + j;           // p in [0,528)
    int tT = (int)((sqrtf(8.f * (float)p + 1.f) - 1.f) * 0.5f);
    while ((tT + 1) * (tT + 2) / 2 <= p) ++tT;
    while (tT * (tT + 1) / 2 > p) --tT;
    int sT = p - tT * (tT + 1) / 2;
    const int t0 = tT * 64, s0 = sT * 64;
    const int rK = sblk * 32 + l31;
    const int t_loc = tgrp * 32 + l31;

    float zacc[16];
#pragma unroll
    for (int r = 0; r < 16; r++) zacc[r] = 0.f;

    bf16x8 qA[12];
    auto QLOAD = [&](int h) {
        const u16* qp = qbuf + ((size_t)(b * 16 + h) * 2048 + t0 + t_loc) * 192 + hi * 8;
#pragma unroll
        for (int kk = 0; kk < 12; kk++) qA[kk] = *(const bf16x8*)(qp + kk * 16);
    };
    auto KSTAGE = [&](int h, int bi) {
        const size_t hrow = (size_t)(b * 16 + h) * 2048;
#pragma unroll
        for (int j2 = 0; j2 < 6; j2++) {
            int idx = (wave * 6 + j2) * 64 + lane;
            int rr2 = idx / 24, cc = idx % 24, cs = cc ^ (rr2 & 7);
            gload_lds16(kbuf + (hrow + s0 + rr2) * 192 + cs * 8, &Ks[bi * 12288 + idx * 8]);
        }
    };
    auto COMPUTE = [&](const u16* K) {
        f32x16 e;
#pragma unroll
        for (int r = 0; r < 16; r++) e[r] = 0.f;
        __builtin_amdgcn_s_setprio(1);
#pragma unroll
        for (int kk = 0; kk < 12; kk++) {
            int slot = (2 * kk + hi) ^ (rK & 7);
            bf16x8 kf = *(const bf16x8*)&K[rK * 192 + slot * 8];
            e = __builtin_amdgcn_mfma_f32_32x32x16_bf16(kf, qA[kk], e, 0, 0, 0);
        }
        __builtin_amdgcn_s_setprio(0);
#pragma unroll
        for (int r = 0; r < 16; r++) zacc[r] += __expf(e[r] * SCALE_QK);
    };

    QLOAD(0);
    KSTAGE(0, 0);
    asm volatile("s_waitcnt vmcnt(0)" ::: "memory");
    __builtin_amdgcn_s_barrier();
#pragma unroll 1
    for (int h = 0; h < 16; ++h) {
        int cur = h & 1;
        if (h < 15) {
            KSTAGE(h + 1, cur ^ 1);
            // newer-than-K(h): Q(h) 12 + K(h+1) 6 = 18 -> K(h) forced complete
            asm volatile("s_waitcnt vmcnt(18)" ::: "memory");
        } else {
            asm volatile("s_waitcnt vmcnt(12)" ::: "memory");
        }
        __builtin_amdgcn_s_barrier();
        __builtin_amdgcn_sched_barrier(0);
        COMPUTE(&Ks[cur * 12288]);   // compiler auto-waits qA's own loads
        __builtin_amdgcn_s_barrier();
        if (h < 15) QLOAD(h + 1);    // reuse qA regs after COMPUTE released them
    }
#pragma unroll
    for (int r = 0; r < 16; r++) {
        int spat = (r & 3) + 8 * (r >> 2) + 4 * hi;
        int sg = s0 + sblk * 32 + spat;
        zbufT[((size_t)b * 2048 + sg) * 2048 + t0 + t_loc] = f2b(__fdividef(1.f, zacc[r]));
    }
}

// ---------------- PV kernel: attnb += sum_{s<=t} exp(x)*rz * v ----------------
// swapped 32x32 QK^T; P in registers; 3-deep K/V + 2-deep Z pipeline, vmcnt(12)
__global__ __launch_bounds__(512, 1)
void attn_pv(const u16* __restrict__ qbuf, const u16* __restrict__ kbuf,
             const u16* __restrict__ vtbuf, const u16* __restrict__ zbufT,
             u16* __restrict__ attnb) {
    __shared__ __align__(16) u16 lds[77824];   // K 3x12288 | V 3x8192 | Z 2x8192 = 152KB
    u16* Ks = lds;                  // [3][12288]
    u16* Vt = lds + 36864;          // [3][8192]
    u16* Zs = lds + 61440;          // [2][8192]
    const int tid = threadIdx.x, lane = tid & 63, wave = tid >> 6;
    const int hi = lane >> 5, l31 = lane & 31;
    const int tgrp = wave & 3, sblk = wave >> 2;
    int id = blockIdx.x;             // 0..255
    int xcd = id & 7, j2 = id >> 3;
    int pr = j2 & 7, g = j2 >> 3;
    int bh = xcd * 4 + g;
    const int b = bh >> 4, h = bh & 15;
    const size_t kvrow = (size_t)bh * 2048;
    const int rK = sblk * 32 + l31;
    const int t_loc = tgrp * 32 + l31;
    const int zg = t_loc >> 3, zoff = t_loc & 7;

    for (int part = 0; part < 2; ++part) {
        const int T = part ? (15 - pr) : pr;
        const int t0p = T * 128, nst = 2 * T + 2;
        const int tg = t0p + t_loc;

        bf16x8 qf[12];
        {
            const u16* qp = qbuf + (kvrow + tg) * 192 + hi * 8;
#pragma unroll
            for (int kk = 0; kk < 12; kk++) qf[kk] = *(const bf16x8*)(qp + kk * 16);
        }
        f32x16 o[4];
#pragma unroll
        for (int db = 0; db < 4; db++)
#pragma unroll
            for (int r = 0; r < 16; r++) o[db][r] = 0.f;

        auto STAGE_KV = [&](int st, int bi) {   // 5 loads/wave
            const int s0 = st * 64;
#pragma unroll
            for (int j = 0; j < 3; j++) {       // K: 24KB
                int idx = (wave * 3 + j) * 64 + lane;
                int rr2 = idx / 24, cc = idx % 24, cs = cc ^ (rr2 & 7);
                gload_lds16(kbuf + (kvrow + s0 + rr2) * 192 + cs * 8, &Ks[bi * 12288 + idx * 8]);
            }
#pragma unroll
            for (int j = 0; j < 2; j++) {       // V^T: 16KB
                int idx = (wave * 2 + j) * 64 + lane;
                int d = idx >> 3, cc = idx & 7, cs = cc ^ (d & 7);
                gload_lds16(vtbuf + ((size_t)bh * 128 + d) * 2048 + s0 + cs * 8, &Vt[bi * 8192 + idx * 8]);
            }
        };
        auto STAGE_Z = [&](int st, int bi) {    // 2 loads/wave
            const int s0 = st * 64;
#pragma unroll
            for (int j = 0; j < 2; j++) {       // Z^T tile [64s][128t]: 16KB
                int idx = (wave * 2 + j) * 64 + lane;
                int sr = idx >> 4, cc = idx & 15, cs = cc ^ (sr & 15);
                gload_lds16(zbufT + ((size_t)b * 2048 + s0 + sr) * 2048 + t0p + cs * 8, &Zs[bi * 8192 + idx * 8]);
            }
        };
        // prologue: FIFO = [Z(0) K(0) V(0)] [K(1) V(1)]
        STAGE_Z(0, 0);
        STAGE_KV(0, 0);
        STAGE_KV(1, 1);             // nst >= 2 always
        int rb = 0;                 // K/V read buffer = st % 3
        for (int st = 0; st < nst; ++st) {
            int cz = st & 1;
            if (st + 2 < nst) {
                STAGE_Z(st + 1, cz ^ 1);
                STAGE_KV(st + 2, rb == 0 ? 2 : rb - 1);   // (st+2)%3
                // newer-than-Z(st): K/V(st+1)=5 + Z(st+1)+K/V(st+2)=7 -> 12
                asm volatile("s_waitcnt vmcnt(12)" ::: "memory");
            } else if (st + 1 < nst) {
                STAGE_Z(st + 1, cz ^ 1);
                // newer-than-Z(st): K/V(st+1)=5 + Z(st+1)=2 -> 7
                asm volatile("s_waitcnt vmcnt(7)" ::: "memory");
            } else {
                asm volatile("s_waitcnt vmcnt(0)" ::: "memory");
            }
            __builtin_amdgcn_s_barrier();
            __builtin_amdgcn_sched_barrier(0);
            const u16* Kc = &Ks[rb * 12288];
            const u16* Vc = &Vt[rb * 8192];
            const u16* Zc = &Zs[cz * 8192];
            // QK^T swapped: S^T[s][t]
            f32x16 sacc;
#pragma unroll
            for (int r = 0; r < 16; r++) sacc[r] = 0.f;
            __builtin_amdgcn_s_setprio(1);
#pragma unroll
            for (int kk = 0; kk < 12; kk++) {
                int slot = (2 * kk + hi) ^ (rK & 7);
                bf16x8 kf = *(const bf16x8*)&Kc[rK * 192 + slot * 8];
                sacc = __builtin_amdgcn_mfma_f32_32x32x16_bf16(kf, qf[kk], sacc, 0, 0, 0);
            }
            __builtin_amdgcn_s_setprio(0);
            // softmax: w = exp * rz (causal), all in-register
            const int s0g = st * 64 + sblk * 32;
            float w[16];
#pragma unroll
            for (int r = 0; r < 16; r++) {
                int spat = (r & 3) + 8 * (r >> 2) + 4 * hi;
                int sr = sblk * 32 + spat;
                float rz = b2f(Zc[sr * 128 + ((zg ^ (sr & 15)) << 3) + zoff]);
                w[r] = (s0g + spat <= tg) ? __expf(sacc[r] * SCALE_QK) * rz : 0.f;
            }
            // pack to PV A-frags (T12): word m of frag holds s_local {hi*8+2m, hi*8+2m+1}
            unsigned pw0 = pk2(w[0], w[1]), pw1 = pk2(w[2], w[3]);
            unsigned pw2 = pk2(w[4], w[5]), pw3 = pk2(w[6], w[7]);
            unsigned pw4 = pk2(w[8], w[9]), pw5 = pk2(w[10], w[11]);
            unsigned pw6 = pk2(w[12], w[13]), pw7 = pk2(w[14], w[15]);
            unsigned a0 = pw0, a1 = pw1, a2 = pw4, a3 = pw5;
            asm volatile("v_permlane32_swap_b32 %0, %1" : "+v"(a0), "+v"(pw2));
            asm volatile("v_permlane32_swap_b32 %0, %1" : "+v"(a1), "+v"(pw3));
            asm volatile("v_permlane32_swap_b32 %0, %1" : "+v"(a2), "+v"(pw6));
            asm volatile("v_permlane32_swap_b32 %0, %1" : "+v"(a3), "+v"(pw7));
            union PU { unsigned u[4]; bf16x8 v; } p0, p1;
            p0.u[0] = a0;  p0.u[1] = a1;  p0.u[2] = pw2; p0.u[3] = pw3;   // s_local 0..15
            p1.u[0] = a2;  p1.u[1] = a3;  p1.u[2] = pw6; p1.u[3] = pw7;   // s_local 16..31
            // PV: o[t][d] += P[t][s] V[s][d], s within THIS wave's sblk half
            __builtin_amdgcn_s_setprio(1);
#pragma unroll
            for (int db = 0; db < 4; db++) {
                int dv = db * 32 + l31;
#pragma unroll
                for (int ks = 0; ks < 2; ks++) {
                    int slot = (sblk * 4 + 2 * ks + hi) ^ (dv & 7);
                    bf16x8 vb = *(const bf16x8*)&Vc[dv * 64 + slot * 8];
                    o[db] = __builtin_amdgcn_mfma_f32_32x32x16_bf16(ks ? p1.v : p0.v, vb, o[db], 0, 0, 0);
                }
            }
            __builtin_amdgcn_s_setprio(0);
            __builtin_amdgcn_s_barrier();
            rb = (rb == 2) ? 0 : rb + 1;
        }
        // epilogue: cross-wave (sblk0 + sblk1) reduce via LDS, add u term, write
        __syncthreads();
        float* red = (float*)lds;   // [128t][128d] f32 = 64KB (aliases K bufs, restaged next part)
        if (sblk == 0) {
#pragma unroll
            for (int db = 0; db < 4; db++)
#pragma unroll
                for (int r = 0; r < 16; r++) {
                    int trow = (r & 3) + 8 * (r >> 2) + 4 * hi;
                    red[(tgrp * 32 + trow) * 128 + db * 32 + l31] = o[db][r];
                }
        }
        __syncthreads();
        if (sblk == 1) {
#pragma unroll
            for (int db = 0; db < 4; db++)
#pragma unroll
                for (int r = 0; r < 16; r++) {
                    int trow = (r & 3) + 8 * (r >> 2) + 4 * hi;
                    float val = o[db][r] + red[(tgrp * 32 + trow) * 128 + db * 32 + l31];
                    size_t oi = ((size_t)b * 2048 + t0p + tgrp * 32 + trow) * 2048 + h * 128 + db * 32 + l31;
                    attnb[oi] = f2b(val + b2f(attnb[oi]));
                }
        }
        __syncthreads();   // red/lds dead before next part's STAGE
    }
}

// ---------------- launch ----------------
extern "C" void kernel_launch(void* const* d_in, const int* in_sizes, int n_in,
                              void* d_out, int out_size, void* d_ws, size_t ws_size,
                              hipStream_t stream) {
    (void)in_sizes; (void)n_in; (void)out_size;
    const float* hidden = (const float*)d_in[0];
    const float* freqs  = (const float*)d_in[1];
    const float* Wq     = (const float*)d_in[3];
    const float* Wkva   = (const float*)d_in[4];
    const float* gamma  = (const float*)d_in[5];
    const float* beta   = (const float*)d_in[6];
    const float* Wkvb   = (const float*)d_in[7];
    const float* Wout   = (const float*)d_in[8];
    float* outp = (float*)d_out;

    char* ws = (char*)d_ws;
    size_t off = 0;
    auto alloc = [&](size_t bytes) -> void* {
        void* p = ws + off; off += (bytes + 255) & ~(size_t)255; return p;
    };
    u16*   hid_b = (u16*)alloc((size_t)MROWS * HID * 2);
    u16*   WqT   = (u16*)alloc((size_t)3072 * 2048 * 2);
    u16*   WkvaT = (u16*)alloc((size_t)640 * 2048 * 2);
    u16*   WkvbT = (u16*)alloc((size_t)4096 * 512 * 2);
    u16*   WoutT = (u16*)alloc((size_t)2048 * 2048 * 2);
    u16*   qbuf  = (u16*)alloc((size_t)BATCH * NHEAD * TSEQ * QK * 2);
    float* kvf   = (float*)alloc((size_t)MROWS * 640 * 4);
    u16*   kvlat = (u16*)alloc((size_t)MROWS * 512 * 2);
    u16*   kbuf  = (u16*)alloc((size_t)BATCH * NHEAD * TSEQ * QK * 2);
    u16*   vbuf  = (u16*)alloc((size_t)BATCH * NHEAD * TSEQ * VD * 2);
    u16*   attnb = (u16*)alloc((size_t)MROWS * 2048 * 2);
    float2* ropetab = (float2*)alloc((size_t)2048 * 32 * 8);
    float* psum  = (float*)alloc((size_t)32 * 16 * 128 * 4);
    float* csuf  = (float*)alloc((size_t)32 * 16 * 128 * 4);
    if (off > ws_size) return;
    // overlays (dead regions by the time they're written):
    u16* zbufT = WqT;     // 16.78 MB spanning WqT+WkvaT+part of WkvbT, free after gemm<0>/<2>
    u16* vtbuf = hid_b;   // 16.78 MB, free after gemm<0>/<1>

    cvt_bf16x8<<<4096, 256, 0, stream>>>(hidden, hid_b, MROWS * HID / 8);
    rope_tab_k<<<256, 256, 0, stream>>>(freqs, ropetab);
    dim3 tb(32, 8);
    transpose_cvt<<<dim3(96, 64), tb, 0, stream>>>(Wq, WqT, 2048, 3072, 3072);
    transpose_cvt<<<dim3(20, 64), tb, 0, stream>>>(Wkva, WkvaT, 2048, 576, 640);
    transpose_cvt<<<dim3(128, 16), tb, 0, stream>>>(Wkvb, WkvbT, 512, 4096, 4096);
    transpose_cvt<<<dim3(64, 64), tb, 0, stream>>>(Wout, WoutT, 2048, 2048, 2048);

    gemm_bt<1><<<dim3(32, 5), 256, 0, stream>>>(hid_b, WkvaT, 2048, kvf, nullptr, nullptr, nullptr);
    gemm_bt<0><<<dim3(32, 24), 256, 0, stream>>>(hid_b, WqT, 2048, qbuf, nullptr, nullptr, ropetab);
    ln_krope<<<MROWS, 256, 0, stream>>>(kvf, gamma, beta, ropetab, kvlat, kbuf);
    gemm_bt<2><<<dim3(32, 32), 256, 0, stream>>>(kvlat, WkvbT, 512, kbuf, vbuf, vtbuf, nullptr);

    suff1<<<dim3(32, 16), 128, 0, stream>>>(vbuf, psum);
    suff2<<<32, 128, 0, stream>>>(psum, csuf);
    suff3<<<dim3(32, 16), 128, 0, stream>>>(vbuf, csuf, attnb);

    z_kernel<<<1056, 256, 0, stream>>>(qbuf, kbuf, zbufT);
    attn_pv<<<256, 512, 0, stream>>>(qbuf, kbuf, vtbuf, zbufT, attnb);

    gemm_bt<3><<<dim3(32, 16), 256, 0, stream>>>(attnb, WoutT, 2048, outp, nullptr, nullptr, nullptr);
}

// Round 10
// 514.087 us; speedup vs baseline: 1.0508x; 1.0508x over previous
//
#include <hip/hip_runtime.h>

typedef unsigned short u16;
typedef short bf16x8 __attribute__((ext_vector_type(8)));
typedef float f32x4 __attribute__((ext_vector_type(4)));
typedef float f32x16 __attribute__((ext_vector_type(16)));
typedef unsigned short u16x8 __attribute__((ext_vector_type(8)));

#define GLOBAL_AS __attribute__((address_space(1)))
#define LDS_AS __attribute__((address_space(3)))
#define DEVINL __device__ __forceinline__

#define BATCH 2
#define TSEQ 2048
#define NHEAD 16
#define QK 192
#define VD 128
#define HID 2048
#define MROWS 4096
#define SCALE_QK 0.07216878364870323f   // 192^-0.5

DEVINL float b2f(u16 u) { union { unsigned i; float f; } x; x.i = ((unsigned)u) << 16; return x.f; }
DEVINL u16 f2b(float f) {
    union { float f; unsigned u; } x; x.f = f;
    unsigned r = x.u + 0x7fffu + ((x.u >> 16) & 1u);
    return (u16)(r >> 16);
}
DEVINL void gload_lds16(const u16* g, u16* l) {
    __builtin_amdgcn_global_load_lds((const GLOBAL_AS unsigned*)g, (LDS_AS unsigned*)l, 16, 0, 0);
}
DEVINL unsigned pk2(float a, float b) {
    unsigned d;
    asm("v_cvt_pk_bf16_f32 %0, %1, %2" : "=v"(d) : "v"(a), "v"(b));
    return d;
}

// ---------------- conversion kernels ----------------

__global__ void cvt_bf16x8(const float* __restrict__ in, u16* __restrict__ out, int n8) {
    int i = blockIdx.x * 256 + threadIdx.x;
    if (i < n8) {
        const float4* p = (const float4*)(in + (size_t)i * 8);
        float4 x = p[0], y = p[1];
        u16x8 o;
        o[0] = f2b(x.x); o[1] = f2b(x.y); o[2] = f2b(x.z); o[3] = f2b(x.w);
        o[4] = f2b(y.x); o[5] = f2b(y.y); o[6] = f2b(y.z); o[7] = f2b(y.w);
        *(u16x8*)(out + (size_t)i * 8) = o;
    }
}

__global__ void rope_tab_k(const float* __restrict__ freqs, float2* __restrict__ tab) {
    int i = blockIdx.x * 256 + threadIdx.x;   // 65536 = 2048*32
    float f = freqs[i], s, c;
    sincosf(f, &s, &c);
    tab[i] = make_float2(c, s);
}

// in: f32 [R][C] row-major -> out: bf16 [Cpad][R], zeros for c >= C
__global__ void transpose_cvt(const float* __restrict__ in, u16* __restrict__ out,
                              int R, int C, int Cpad) {
    __shared__ float tile[32][33];
    int c0 = blockIdx.x * 32, r0 = blockIdx.y * 32;
    int tx = threadIdx.x, ty = threadIdx.y;   // 32 x 8
#pragma unroll
    for (int j = 0; j < 4; j++) {
        int r = r0 + ty + j * 8, c = c0 + tx;
        tile[ty + j * 8][tx] = (c < C) ? in[(size_t)r * C + c] : 0.f;
    }
    __syncthreads();
#pragma unroll
    for (int j = 0; j < 4; j++) {
        int oc = c0 + ty + j * 8;
        int orr = r0 + tx;
        if (oc < Cpad) out[(size_t)oc * R + orr] = f2b(tile[tx][ty + j * 8]);
    }
}

// ---------------- GEMM: C = A[M][K] * BT[N][K]^T ----------------
// MODE 0: q epilogue (fused RoPE via tab) -> qbuf bf16 (b,h,t,192)
// MODE 1: kv f32 -> [row][640]
// MODE 2: kvb -> k_nope into kbuf + v into vbuf AND vtbuf (out2)
// MODE 3: f32 out [row][2048]
template<int MODE>
__global__ __launch_bounds__(256)
void gemm_bt(const u16* __restrict__ A, const u16* __restrict__ BT, int Kdim,
             void* __restrict__ out0, void* __restrict__ out1, void* __restrict__ out2,
             const float2* __restrict__ tab) {
    __shared__ __align__(16) u16 As[128 * 32];
    __shared__ __align__(16) u16 Bs[128 * 32];
    const int tid = threadIdx.x, lane = tid & 63, wave = tid >> 6;
    const int m0 = blockIdx.x * 128, n0 = blockIdx.y * 128;
    const int wr = wave >> 1, wc = wave & 1;

    f32x4 acc[4][4];
#pragma unroll
    for (int i = 0; i < 4; i++)
#pragma unroll
        for (int j = 0; j < 4; j++) acc[i][j] = f32x4{0.f, 0.f, 0.f, 0.f};

    const int e0 = (wave * 2 + 0) * 512 + lane * 8;
    const int e1 = (wave * 2 + 1) * 512 + lane * 8;
    const u16* gA0 = A + (size_t)(m0 + (e0 >> 5)) * Kdim + (e0 & 31);
    const u16* gA1 = A + (size_t)(m0 + (e1 >> 5)) * Kdim + (e1 & 31);
    const u16* gB0 = BT + (size_t)(n0 + (e0 >> 5)) * Kdim + (e0 & 31);
    const u16* gB1 = BT + (size_t)(n0 + (e1 >> 5)) * Kdim + (e1 & 31);
    u16* lA0 = &As[(wave * 2 + 0) * 512];
    u16* lA1 = &As[(wave * 2 + 1) * 512];
    u16* lB0 = &Bs[(wave * 2 + 0) * 512];
    u16* lB1 = &Bs[(wave * 2 + 1) * 512];

    const int arow = lane & 15, koff = (lane >> 4) * 8;

    for (int k0 = 0; k0 < Kdim; k0 += 32) {
        gload_lds16(gA0, lA0); gload_lds16(gA1, lA1);
        gload_lds16(gB0, lB0); gload_lds16(gB1, lB1);
        gA0 += 32; gA1 += 32; gB0 += 32; gB1 += 32;
        asm volatile("s_waitcnt vmcnt(0)" ::: "memory");
        __syncthreads();
        bf16x8 af[4], bfr[4];
#pragma unroll
        for (int i = 0; i < 4; i++)
            af[i] = *(const bf16x8*)&As[(wr * 64 + i * 16 + arow) * 32 + koff];
#pragma unroll
        for (int j = 0; j < 4; j++)
            bfr[j] = *(const bf16x8*)&Bs[(wc * 64 + j * 16 + arow) * 32 + koff];
#pragma unroll
        for (int i = 0; i < 4; i++)
#pragma unroll
            for (int j = 0; j < 4; j++)
                acc[i][j] = __builtin_amdgcn_mfma_f32_16x16x32_bf16(af[i], bfr[j], acc[i][j], 0, 0, 0);
        __syncthreads();
    }

#pragma unroll
    for (int i = 0; i < 4; i++)
#pragma unroll
        for (int j = 0; j < 4; j++)
#pragma unroll
            for (int r = 0; r < 4; r++) {
                int row = m0 + wr * 64 + i * 16 + (lane >> 4) * 4 + r;
                int col = n0 + wc * 64 + j * 16 + (lane & 15);
                float v = acc[i][j][r];
                if constexpr (MODE == 0) {
                    int h = col / 192, d = col % 192;
                    int b = row >> 11, t = row & 2047;
                    float vv = v;
                    float pv = __shfl_xor(v, 1);   // RoPE partner (same row, col^1)
                    if (d >= 128) {
                        float2 cs = tab[t * 32 + ((d - 128) >> 1)];
                        vv = v * cs.x + pv * ((lane & 1) ? cs.y : -cs.y);
                    }
                    ((u16*)out0)[((size_t)(b * 16 + h) * 2048 + t) * 192 + d] = f2b(vv);
                } else if constexpr (MODE == 1) {
                    ((float*)out0)[(size_t)row * 640 + col] = v;
                } else if constexpr (MODE == 2) {
                    int h = col >> 8, d = col & 255;
                    int b = row >> 11, t = row & 2047;
                    size_t base = (size_t)(b * 16 + h) * 2048 + t;
                    if (d < 128) ((u16*)out0)[base * 192 + d] = f2b(v);
                    else {
                        u16 bv = f2b(v);
                        ((u16*)out1)[base * 128 + (d - 128)] = bv;
                        ((u16*)out2)[((size_t)(b * 16 + h) * 128 + (d - 128)) * 2048 + t] = bv;
                    }
                } else {
                    ((float*)out0)[(size_t)row * 2048 + col] = v;
                }
            }
}

// ---------------- LayerNorm(512) + k_rope broadcast ----------------
__global__ __launch_bounds__(256)
void ln_krope(const float* __restrict__ kvf, const float* __restrict__ gamma,
              const float* __restrict__ beta, const float2* __restrict__ tab,
              u16* __restrict__ kvlat, u16* __restrict__ kbuf) {
    int row = blockIdx.x, tid = threadIdx.x;
    const float* x = kvf + (size_t)row * 640;
    float v0 = x[tid], v1 = x[tid + 256];
    float s = v0 + v1, sq = v0 * v0 + v1 * v1;
#pragma unroll
    for (int off = 1; off < 64; off <<= 1) { s += __shfl_xor(s, off); sq += __shfl_xor(sq, off); }
    __shared__ float ssum[4], ssq[4];
    if ((tid & 63) == 0) { ssum[tid >> 6] = s; ssq[tid >> 6] = sq; }
    __syncthreads();
    s = ssum[0] + ssum[1] + ssum[2] + ssum[3];
    sq = ssq[0] + ssq[1] + ssq[2] + ssq[3];
    float mu = s * (1.f / 512.f);
    float var = sq * (1.f / 512.f) - mu * mu;
    float rs = rsqrtf(var + 1e-5f);
    kvlat[(size_t)row * 512 + tid] = f2b((v0 - mu) * rs * gamma[tid] + beta[tid]);
    kvlat[(size_t)row * 512 + tid + 256] = f2b((v1 - mu) * rs * gamma[tid + 256] + beta[tid + 256]);
    if (tid < 32) {
        int t = row & 2047, b = row >> 11;
        float x1 = x[512 + 2 * tid], x2 = x[512 + 2 * tid + 1];
        float2 cs = tab[t * 32 + tid];
        u16 u1 = f2b(x1 * cs.x - x2 * cs.y), u2 = f2b(x1 * cs.y + x2 * cs.x);
        for (int h = 0; h < 16; ++h) {
            size_t base = ((size_t)(b * 16 + h) * 2048 + t) * 192 + 128 + 2 * tid;
            kbuf[base] = u1; kbuf[base + 1] = u2;
        }
    }
}

// ---------------- parallel suffix scan of V -> u term written into attnb ----------------
__global__ void suff1(const u16* __restrict__ vbuf, float* __restrict__ psum) {
    int bh = blockIdx.x, c = blockIdx.y, d = threadIdx.x;   // 128 threads
    float s = 0.f;
    const u16* vp = vbuf + ((size_t)bh * 2048 + c * 128) * 128 + d;
    for (int tt = 0; tt < 128; ++tt) s += b2f(vp[(size_t)tt * 128]);
    psum[((size_t)bh * 16 + c) * 128 + d] = s;
}
__global__ void suff2(const float* __restrict__ psum, float* __restrict__ csuf) {
    int bh = blockIdx.x, d = threadIdx.x;
    float run = 0.f;
    for (int c = 15; c >= 0; --c) {
        csuf[((size_t)bh * 16 + c) * 128 + d] = run;
        run += psum[((size_t)bh * 16 + c) * 128 + d];
    }
}
__global__ void suff3(const u16* __restrict__ vbuf, const float* __restrict__ csuf,
                      u16* __restrict__ attnb) {
    int bh = blockIdx.x, c = blockIdx.y, d = threadIdx.x;
    int b = bh >> 4, h = bh & 15;
    float run = csuf[((size_t)bh * 16 + c) * 128 + d];
    for (int tt = 127; tt >= 0; --tt) {
        int t = c * 128 + tt;
        attnb[((size_t)b * 2048 + t) * 2048 + h * 128 + d] = f2b(run * 0.0625f);
        run += b2f(vbuf[((size_t)bh * 2048 + t) * 128 + d]);
    }
}

// ---------------- Z kernel: zbufT[b][s][t] = 1 / sum_h exp(SCALE*q.k), bf16 ----------------
// s-grouped: block owns (tT, 2 consecutive s-tiles); Q regs reused across both
// -> Q traffic halves. dbuf K LDS (48KB -> 3 blocks/CU), counted vmcnt chain.
__global__ __launch_bounds__(256, 3)
void z_kernel(const u16* __restrict__ qbuf, const u16* __restrict__ kbuf,
              u16* __restrict__ zbufT) {
    __shared__ __align__(16) u16 Ks[2 * 12288];
    const int tid = threadIdx.x, lane = tid & 63, wave = tid >> 6;
    const int hi = lane >> 5, l31 = lane & 31;
    const int tgrp = wave & 1, sblk = wave >> 1;
    int id = blockIdx.x;            // 0..543
    int b = id & 1, p = id >> 1;    // p in [0,272)
    int tT = 0;
    for (;;) { int cnt = (tT + 2) >> 1; if (p < cnt) break; p -= cnt; ++tT; }
    const int g2 = p * 2;           // first s-tile of the group
    const int ns = ((tT + 1 - g2) >= 2) ? 2 : 1;
    const int t0 = tT * 64;
    const int rK = sblk * 32 + l31;
    const int t_loc = tgrp * 32 + l31;

    bf16x8 qA[12];
    auto QLOAD = [&](int h) {
        const u16* qp = qbuf + ((size_t)(b * 16 + h) * 2048 + t0 + t_loc) * 192 + hi * 8;
#pragma unroll
        for (int kk = 0; kk < 12; kk++) qA[kk] = *(const bf16x8*)(qp + kk * 16);
    };
    auto KSTAGE = [&](int h, int st, int bi) {
        const size_t hrow = (size_t)(b * 16 + h) * 2048;
        const int s0 = st * 64;
#pragma unroll
        for (int j2 = 0; j2 < 6; j2++) {
            int idx = (wave * 6 + j2) * 64 + lane;
            int rr2 = idx / 24, cc = idx % 24, cs = cc ^ (rr2 & 7);
            gload_lds16(kbuf + (hrow + s0 + rr2) * 192 + cs * 8, &Ks[bi * 12288 + idx * 8]);
        }
    };
    f32x16 za0, za1;
#pragma unroll
    for (int r = 0; r < 16; r++) { za0[r] = 0.f; za1[r] = 0.f; }
    auto COMPUTE = [&](f32x16& za, const u16* K) {
        f32x16 e;
#pragma unroll
        for (int r = 0; r < 16; r++) e[r] = 0.f;
        __builtin_amdgcn_s_setprio(1);
#pragma unroll
        for (int kk = 0; kk < 12; kk++) {
            int slot = (2 * kk + hi) ^ (rK & 7);
            bf16x8 kf = *(const bf16x8*)&K[rK * 192 + slot * 8];
            e = __builtin_amdgcn_mfma_f32_32x32x16_bf16(kf, qA[kk], e, 0, 0, 0);
        }
        __builtin_amdgcn_s_setprio(0);
#pragma unroll
        for (int r = 0; r < 16; r++) za[r] += __expf(e[r] * SCALE_QK);
    };

    QLOAD(0);
    KSTAGE(0, g2, 0);
    asm volatile("s_waitcnt vmcnt(0)" ::: "memory");
    __builtin_amdgcn_s_barrier();
    int kb = 0;
#pragma unroll 1
    for (int h = 0; h < 16; ++h) {
        // ---- j = 0 (s-tile g2) ----
        if (ns == 2)      KSTAGE(h, g2 + 1, kb ^ 1);
        else if (h < 15)  KSTAGE(h + 1, g2, kb ^ 1);
        if (ns == 2 || h < 15) {
            if (h > 0) { asm volatile("s_waitcnt vmcnt(18)" ::: "memory"); }
            else       { asm volatile("s_waitcnt vmcnt(6)"  ::: "memory"); }
        } else {
            asm volatile("s_waitcnt vmcnt(12)" ::: "memory");
        }
        __builtin_amdgcn_s_barrier();
        __builtin_amdgcn_sched_barrier(0);
        COMPUTE(za0, &Ks[kb * 12288]);
        __builtin_amdgcn_s_barrier();
        if (ns == 1 && h < 15) QLOAD(h + 1);
        kb ^= 1;
        // ---- j = 1 (s-tile g2+1) ----
        if (ns == 2) {
            if (h < 15) {
                KSTAGE(h + 1, g2, kb ^ 1);
                asm volatile("s_waitcnt vmcnt(6)" ::: "memory");
            } else {
                asm volatile("s_waitcnt vmcnt(0)" ::: "memory");
            }
            __builtin_amdgcn_s_barrier();
            __builtin_amdgcn_sched_barrier(0);
            COMPUTE(za1, &Ks[kb * 12288]);
            __builtin_amdgcn_s_barrier();
            if (h < 15) QLOAD(h + 1);
            kb ^= 1;
        }
    }
#pragma unroll
    for (int r = 0; r < 16; r++) {
        int spat = (r & 3) + 8 * (r >> 2) + 4 * hi;
        int sg = g2 * 64 + sblk * 32 + spat;
        zbufT[((size_t)b * 2048 + sg) * 2048 + t0 + t_loc] = f2b(__fdividef(1.f, za0[r]));
    }
    if (ns == 2) {
#pragma unroll
        for (int r = 0; r < 16; r++) {
            int spat = (r & 3) + 8 * (r >> 2) + 4 * hi;
            int sg = (g2 + 1) * 64 + sblk * 32 + spat;
            zbufT[((size_t)b * 2048 + sg) * 2048 + t0 + t_loc] = f2b(__fdividef(1.f, za1[r]));
        }
    }
}

// ---------------- PV kernel: attnb += sum_{s<=t} exp(x)*rz * v ----------------
// (round-8 schedule: 2-deep K/V/Z dbuf, vmcnt(7); 112KB LDS)
__global__ __launch_bounds__(512, 1)
void attn_pv(const u16* __restrict__ qbuf, const u16* __restrict__ kbuf,
             const u16* __restrict__ vtbuf, const u16* __restrict__ zbufT,
             u16* __restrict__ attnb) {
    __shared__ __align__(16) u16 lds[57344];   // K 2x12288 | V 2x8192 | Z 2x8192 (112KB)
    u16* Ks = lds;
    u16* Vt = lds + 24576;
    u16* Zs = lds + 40960;
    const int tid = threadIdx.x, lane = tid & 63, wave = tid >> 6;
    const int hi = lane >> 5, l31 = lane & 31;
    const int tgrp = wave & 3, sblk = wave >> 2;
    int id = blockIdx.x;             // 0..255
    int xcd = id & 7, j2 = id >> 3;
    int pr = j2 & 7, g = j2 >> 3;
    int bh = xcd * 4 + g;
    const int b = bh >> 4, h = bh & 15;
    const size_t kvrow = (size_t)bh * 2048;
    const int rK = sblk * 32 + l31;
    const int t_loc = tgrp * 32 + l31;
    const int zg = t_loc >> 3, zoff = t_loc & 7;

    for (int part = 0; part < 2; ++part) {
        const int T = part ? (15 - pr) : pr;
        const int t0p = T * 128, nst = 2 * T + 2;
        const int tg = t0p + t_loc;

        bf16x8 qf[12];
        {
            const u16* qp = qbuf + (kvrow + tg) * 192 + hi * 8;
#pragma unroll
            for (int kk = 0; kk < 12; kk++) qf[kk] = *(const bf16x8*)(qp + kk * 16);
        }
        f32x16 o[4];
#pragma unroll
        for (int db = 0; db < 4; db++)
#pragma unroll
            for (int r = 0; r < 16; r++) o[db][r] = 0.f;

        auto STAGE = [&](int st, int bi) {
            const int s0 = st * 64;
#pragma unroll
            for (int j = 0; j < 3; j++) {      // K: 24KB
                int idx = (wave * 3 + j) * 64 + lane;
                int rr2 = idx / 24, cc = idx % 24, cs = cc ^ (rr2 & 7);
                gload_lds16(kbuf + (kvrow + s0 + rr2) * 192 + cs * 8, &Ks[bi * 12288 + idx * 8]);
            }
#pragma unroll
            for (int j = 0; j < 2; j++) {      // V^T: 16KB
                int idx = (wave * 2 + j) * 64 + lane;
                int d = idx >> 3, cc = idx & 7, cs = cc ^ (d & 7);
                gload_lds16(vtbuf + ((size_t)bh * 128 + d) * 2048 + s0 + cs * 8, &Vt[bi * 8192 + idx * 8]);
            }
#pragma unroll
            for (int j = 0; j < 2; j++) {      // Z^T tile [64s][128t]: 16KB
                int idx = (wave * 2 + j) * 64 + lane;
                int sr = idx >> 4, cc = idx & 15, cs = cc ^ (sr & 15);
                gload_lds16(zbufT + ((size_t)b * 2048 + s0 + sr) * 2048 + t0p + cs * 8, &Zs[bi * 8192 + idx * 8]);
            }
        };
        STAGE(0, 0);
        for (int st = 0; st < nst; ++st) {
            int cur = st & 1;
            if (st + 1 < nst) {
                STAGE(st + 1, cur ^ 1);
                asm volatile("s_waitcnt vmcnt(7)" ::: "memory");
            } else {
                asm volatile("s_waitcnt vmcnt(0)" ::: "memory");
            }
            __builtin_amdgcn_s_barrier();
            __builtin_amdgcn_sched_barrier(0);
            const u16* Kc = &Ks[cur * 12288];
            const u16* Vc = &Vt[cur * 8192];
            const u16* Zc = &Zs[cur * 8192];
            // QK^T swapped: S^T[s][t]
            f32x16 sacc;
#pragma unroll
            for (int r = 0; r < 16; r++) sacc[r] = 0.f;
            __builtin_amdgcn_s_setprio(1);
#pragma unroll
            for (int kk = 0; kk < 12; kk++) {
                int slot = (2 * kk + hi) ^ (rK & 7);
                bf16x8 kf = *(const bf16x8*)&Kc[rK * 192 + slot * 8];
                sacc = __builtin_amdgcn_mfma_f32_32x32x16_bf16(kf, qf[kk], sacc, 0, 0, 0);
            }
            __builtin_amdgcn_s_setprio(0);
            // softmax: w = exp * rz (causal), all in-register
            const int s0g = st * 64 + sblk * 32;
            float w[16];
#pragma unroll
            for (int r = 0; r < 16; r++) {
                int spat = (r & 3) + 8 * (r >> 2) + 4 * hi;
                int sr = sblk * 32 + spat;
                float rz = b2f(Zc[sr * 128 + ((zg ^ (sr & 15)) << 3) + zoff]);
                w[r] = (s0g + spat <= tg) ? __expf(sacc[r] * SCALE_QK) * rz : 0.f;
            }
            // pack to PV A-frags (T12): word m of frag holds s_local {hi*8+2m, hi*8+2m+1}
            unsigned pw0 = pk2(w[0], w[1]), pw1 = pk2(w[2], w[3]);
            unsigned pw2 = pk2(w[4], w[5]), pw3 = pk2(w[6], w[7]);
            unsigned pw4 = pk2(w[8], w[9]), pw5 = pk2(w[10], w[11]);
            unsigned pw6 = pk2(w[12], w[13]), pw7 = pk2(w[14], w[15]);
            unsigned a0 = pw0, a1 = pw1, a2 = pw4, a3 = pw5;
            asm volatile("v_permlane32_swap_b32 %0, %1" : "+v"(a0), "+v"(pw2));
            asm volatile("v_permlane32_swap_b32 %0, %1" : "+v"(a1), "+v"(pw3));
            asm volatile("v_permlane32_swap_b32 %0, %1" : "+v"(a2), "+v"(pw6));
            asm volatile("v_permlane32_swap_b32 %0, %1" : "+v"(a3), "+v"(pw7));
            union PU { unsigned u[4]; bf16x8 v; } p0, p1;
            p0.u[0] = a0;  p0.u[1] = a1;  p0.u[2] = pw2; p0.u[3] = pw3;   // s_local 0..15
            p1.u[0] = a2;  p1.u[1] = a3;  p1.u[2] = pw6; p1.u[3] = pw7;   // s_local 16..31
            // PV: o[t][d] += P[t][s] V[s][d], s within THIS wave's sblk half
            __builtin_amdgcn_s_setprio(1);
#pragma unroll
            for (int db = 0; db < 4; db++) {
                int dv = db * 32 + l31;
#pragma unroll
                for (int ks = 0; ks < 2; ks++) {
                    int slot = (sblk * 4 + 2 * ks + hi) ^ (dv & 7);
                    bf16x8 vb = *(const bf16x8*)&Vc[dv * 64 + slot * 8];
                    o[db] = __builtin_amdgcn_mfma_f32_32x32x16_bf16(ks ? p1.v : p0.v, vb, o[db], 0, 0, 0);
                }
            }
            __builtin_amdgcn_s_setprio(0);
            __builtin_amdgcn_s_barrier();
        }
        // epilogue: cross-wave (sblk0 + sblk1) reduce via LDS, add u term, write
        __syncthreads();
        float* red = (float*)lds;   // [128t][128d] f32 = 64KB
        if (sblk == 0) {
#pragma unroll
            for (int db = 0; db < 4; db++)
#pragma unroll
                for (int r = 0; r < 16; r++) {
                    int trow = (r & 3) + 8 * (r >> 2) + 4 * hi;
                    red[(tgrp * 32 + trow) * 128 + db * 32 + l31] = o[db][r];
                }
        }
        __syncthreads();
        if (sblk == 1) {
#pragma unroll
            for (int db = 0; db < 4; db++)
#pragma unroll
                for (int r = 0; r < 16; r++) {
                    int trow = (r & 3) + 8 * (r >> 2) + 4 * hi;
                    float val = o[db][r] + red[(tgrp * 32 + trow) * 128 + db * 32 + l31];
                    size_t oi = ((size_t)b * 2048 + t0p + tgrp * 32 + trow) * 2048 + h * 128 + db * 32 + l31;
                    attnb[oi] = f2b(val + b2f(attnb[oi]));
                }
        }
        __syncthreads();   // red/lds dead before next part's STAGE
    }
}

// ---------------- launch ----------------
extern "C" void kernel_launch(void* const* d_in, const int* in_sizes, int n_in,
                              void* d_out, int out_size, void* d_ws, size_t ws_size,
                              hipStream_t stream) {
    (void)in_sizes; (void)n_in; (void)out_size;
    const float* hidden = (const float*)d_in[0];
    const float* freqs  = (const float*)d_in[1];
    const float* Wq     = (const float*)d_in[3];
    const float* Wkva   = (const float*)d_in[4];
    const float* gamma  = (const float*)d_in[5];
    const float* beta   = (const float*)d_in[6];
    const float* Wkvb   = (const float*)d_in[7];
    const float* Wout   = (const float*)d_in[8];
    float* outp = (float*)d_out;

    char* ws = (char*)d_ws;
    size_t off = 0;
    auto alloc = [&](size_t bytes) -> void* {
        void* p = ws + off; off += (bytes + 255) & ~(size_t)255; return p;
    };
    u16*   hid_b = (u16*)alloc((size_t)MROWS * HID * 2);
    u16*   WqT   = (u16*)alloc((size_t)3072 * 2048 * 2);
    u16*   WkvaT = (u16*)alloc((size_t)640 * 2048 * 2);
    u16*   WkvbT = (u16*)alloc((size_t)4096 * 512 * 2);
    u16*   WoutT = (u16*)alloc((size_t)2048 * 2048 * 2);
    u16*   qbuf  = (u16*)alloc((size_t)BATCH * NHEAD * TSEQ * QK * 2);
    float* kvf   = (float*)alloc((size_t)MROWS * 640 * 4);
    u16*   kvlat = (u16*)alloc((size_t)MROWS * 512 * 2);
    u16*   kbuf  = (u16*)alloc((size_t)BATCH * NHEAD * TSEQ * QK * 2);
    u16*   vbuf  = (u16*)alloc((size_t)BATCH * NHEAD * TSEQ * VD * 2);
    u16*   attnb = (u16*)alloc((size_t)MROWS * 2048 * 2);
    float2* ropetab = (float2*)alloc((size_t)2048 * 32 * 8);
    float* psum  = (float*)alloc((size_t)32 * 16 * 128 * 4);
    float* csuf  = (float*)alloc((size_t)32 * 16 * 128 * 4);
    if (off > ws_size) return;
    // overlays (dead regions by the time they're written):
    u16* zbufT = WqT;     // 16.78 MB spanning WqT+WkvaT+part of WkvbT, free after gemm<0>/<2>
    u16* vtbuf = hid_b;   // 16.78 MB, free after gemm<0>/<1>

    cvt_bf16x8<<<4096, 256, 0, stream>>>(hidden, hid_b, MROWS * HID / 8);
    rope_tab_k<<<256, 256, 0, stream>>>(freqs, ropetab);
    dim3 tb(32, 8);
    transpose_cvt<<<dim3(96, 64), tb, 0, stream>>>(Wq, WqT, 2048, 3072, 3072);
    transpose_cvt<<<dim3(20, 64), tb, 0, stream>>>(Wkva, WkvaT, 2048, 576, 640);
    transpose_cvt<<<dim3(128, 16), tb, 0, stream>>>(Wkvb, WkvbT, 512, 4096, 4096);
    transpose_cvt<<<dim3(64, 64), tb, 0, stream>>>(Wout, WoutT, 2048, 2048, 2048);

    gemm_bt<1><<<dim3(32, 5), 256, 0, stream>>>(hid_b, WkvaT, 2048, kvf, nullptr, nullptr, nullptr);
    gemm_bt<0><<<dim3(32, 24), 256, 0, stream>>>(hid_b, WqT, 2048, qbuf, nullptr, nullptr, ropetab);
    ln_krope<<<MROWS, 256, 0, stream>>>(kvf, gamma, beta, ropetab, kvlat, kbuf);
    gemm_bt<2><<<dim3(32, 32), 256, 0, stream>>>(kvlat, WkvbT, 512, kbuf, vbuf, vtbuf, nullptr);

    suff1<<<dim3(32, 16), 128, 0, stream>>>(vbuf, psum);
    suff2<<<32, 128, 0, stream>>>(psum, csuf);
    suff3<<<dim3(32, 16), 128, 0, stream>>>(vbuf, csuf, attnb);

    z_kernel<<<544, 256, 0, stream>>>(qbuf, kbuf, zbufT);
    attn_pv<<<256, 512, 0, stream>>>(qbuf, kbuf, vtbuf, zbufT, attnb);

    gemm_bt<3><<<dim3(32, 16), 256, 0, stream>>>(attnb, WoutT, 2048, outp, nullptr, nullptr, nullptr);
}

// Round 11
// 493.020 us; speedup vs baseline: 1.0957x; 1.0427x over previous
//
#include <hip/hip_runtime.h>

typedef unsigned short u16;
typedef short bf16x8 __attribute__((ext_vector_type(8)));
typedef float f32x4 __attribute__((ext_vector_type(4)));
typedef float f32x16 __attribute__((ext_vector_type(16)));
typedef unsigned short u16x8 __attribute__((ext_vector_type(8)));
typedef unsigned short u16x4 __attribute__((ext_vector_type(4)));

#define GLOBAL_AS __attribute__((address_space(1)))
#define LDS_AS __attribute__((address_space(3)))
#define DEVINL __device__ __forceinline__

#define BATCH 2
#define TSEQ 2048
#define NHEAD 16
#define QK 192
#define VD 128
#define HID 2048
#define MROWS 4096
#define SCALE_QK 0.07216878364870323f   // 192^-0.5

DEVINL float b2f(u16 u) { union { unsigned i; float f; } x; x.i = ((unsigned)u) << 16; return x.f; }
DEVINL u16 f2b(float f) {
    union { float f; unsigned u; } x; x.f = f;
    unsigned r = x.u + 0x7fffu + ((x.u >> 16) & 1u);
    return (u16)(r >> 16);
}
DEVINL void gload_lds16(const u16* g, u16* l) {
    __builtin_amdgcn_global_load_lds((const GLOBAL_AS unsigned*)g, (LDS_AS unsigned*)l, 16, 0, 0);
}
DEVINL unsigned pk2(float a, float b) {
    unsigned d;
    asm("v_cvt_pk_bf16_f32 %0, %1, %2" : "=v"(d) : "v"(a), "v"(b));
    return d;
}

// ---------------- conversion kernels ----------------

__global__ void cvt_bf16x8(const float* __restrict__ in, u16* __restrict__ out, int n8) {
    int i = blockIdx.x * 256 + threadIdx.x;
    if (i < n8) {
        const float4* p = (const float4*)(in + (size_t)i * 8);
        float4 x = p[0], y = p[1];
        u16x8 o;
        o[0] = f2b(x.x); o[1] = f2b(x.y); o[2] = f2b(x.z); o[3] = f2b(x.w);
        o[4] = f2b(y.x); o[5] = f2b(y.y); o[6] = f2b(y.z); o[7] = f2b(y.w);
        *(u16x8*)(out + (size_t)i * 8) = o;
    }
}

__global__ void rope_tab_k(const float* __restrict__ freqs, float2* __restrict__ tab) {
    int i = blockIdx.x * 256 + threadIdx.x;   // 65536 = 2048*32
    float f = freqs[i], s, c;
    sincosf(f, &s, &c);
    tab[i] = make_float2(c, s);
}

// in: f32 [R][C] row-major -> out: bf16 [Cpad][R], zeros for c >= C
__global__ void transpose_cvt(const float* __restrict__ in, u16* __restrict__ out,
                              int R, int C, int Cpad) {
    __shared__ float tile[32][33];
    int c0 = blockIdx.x * 32, r0 = blockIdx.y * 32;
    int tx = threadIdx.x, ty = threadIdx.y;   // 32 x 8
#pragma unroll
    for (int j = 0; j < 4; j++) {
        int r = r0 + ty + j * 8, c = c0 + tx;
        tile[ty + j * 8][tx] = (c < C) ? in[(size_t)r * C + c] : 0.f;
    }
    __syncthreads();
#pragma unroll
    for (int j = 0; j < 4; j++) {
        int oc = c0 + ty + j * 8;
        int orr = r0 + tx;
        if (oc < Cpad) out[(size_t)oc * R + orr] = f2b(tile[tx][ty + j * 8]);
    }
}

// ---------------- GEMM: C = A[M][K] * BT[N][K]^T ----------------
// MODE 0: q epilogue (fused RoPE via tab) -> qbuf bf16 (b,h,t,192)
// MODE 1: kv f32 -> [row][640]
// MODE 2: kvb -> k_nope into kbuf + v into vbuf AND vtbuf (out2)
// MODE 3: f32 out [row][2048]
template<int MODE>
__global__ __launch_bounds__(256)
void gemm_bt(const u16* __restrict__ A, const u16* __restrict__ BT, int Kdim,
             void* __restrict__ out0, void* __restrict__ out1, void* __restrict__ out2,
             const float2* __restrict__ tab) {
    __shared__ __align__(16) u16 As[128 * 32];
    __shared__ __align__(16) u16 Bs[128 * 32];
    const int tid = threadIdx.x, lane = tid & 63, wave = tid >> 6;
    const int m0 = blockIdx.x * 128, n0 = blockIdx.y * 128;
    const int wr = wave >> 1, wc = wave & 1;

    f32x4 acc[4][4];
#pragma unroll
    for (int i = 0; i < 4; i++)
#pragma unroll
        for (int j = 0; j < 4; j++) acc[i][j] = f32x4{0.f, 0.f, 0.f, 0.f};

    const int e0 = (wave * 2 + 0) * 512 + lane * 8;
    const int e1 = (wave * 2 + 1) * 512 + lane * 8;
    const u16* gA0 = A + (size_t)(m0 + (e0 >> 5)) * Kdim + (e0 & 31);
    const u16* gA1 = A + (size_t)(m0 + (e1 >> 5)) * Kdim + (e1 & 31);
    const u16* gB0 = BT + (size_t)(n0 + (e0 >> 5)) * Kdim + (e0 & 31);
    const u16* gB1 = BT + (size_t)(n0 + (e1 >> 5)) * Kdim + (e1 & 31);
    u16* lA0 = &As[(wave * 2 + 0) * 512];
    u16* lA1 = &As[(wave * 2 + 1) * 512];
    u16* lB0 = &Bs[(wave * 2 + 0) * 512];
    u16* lB1 = &Bs[(wave * 2 + 1) * 512];

    const int arow = lane & 15, koff = (lane >> 4) * 8;

    for (int k0 = 0; k0 < Kdim; k0 += 32) {
        gload_lds16(gA0, lA0); gload_lds16(gA1, lA1);
        gload_lds16(gB0, lB0); gload_lds16(gB1, lB1);
        gA0 += 32; gA1 += 32; gB0 += 32; gB1 += 32;
        asm volatile("s_waitcnt vmcnt(0)" ::: "memory");
        __syncthreads();
        bf16x8 af[4], bfr[4];
#pragma unroll
        for (int i = 0; i < 4; i++)
            af[i] = *(const bf16x8*)&As[(wr * 64 + i * 16 + arow) * 32 + koff];
#pragma unroll
        for (int j = 0; j < 4; j++)
            bfr[j] = *(const bf16x8*)&Bs[(wc * 64 + j * 16 + arow) * 32 + koff];
#pragma unroll
        for (int i = 0; i < 4; i++)
#pragma unroll
            for (int j = 0; j < 4; j++)
                acc[i][j] = __builtin_amdgcn_mfma_f32_16x16x32_bf16(af[i], bfr[j], acc[i][j], 0, 0, 0);
        __syncthreads();
    }

#pragma unroll
    for (int i = 0; i < 4; i++)
#pragma unroll
        for (int j = 0; j < 4; j++)
#pragma unroll
            for (int r = 0; r < 4; r++) {
                int row = m0 + wr * 64 + i * 16 + (lane >> 4) * 4 + r;
                int col = n0 + wc * 64 + j * 16 + (lane & 15);
                float v = acc[i][j][r];
                if constexpr (MODE == 0) {
                    int h = col / 192, d = col % 192;
                    int b = row >> 11, t = row & 2047;
                    float vv = v;
                    float pv = __shfl_xor(v, 1);   // RoPE partner (same row, col^1)
                    if (d >= 128) {
                        float2 cs = tab[t * 32 + ((d - 128) >> 1)];
                        vv = v * cs.x + pv * ((lane & 1) ? cs.y : -cs.y);
                    }
                    ((u16*)out0)[((size_t)(b * 16 + h) * 2048 + t) * 192 + d] = f2b(vv);
                } else if constexpr (MODE == 1) {
                    ((float*)out0)[(size_t)row * 640 + col] = v;
                } else if constexpr (MODE == 2) {
                    int h = col >> 8, d = col & 255;
                    int b = row >> 11, t = row & 2047;
                    size_t base = (size_t)(b * 16 + h) * 2048 + t;
                    if (d < 128) ((u16*)out0)[base * 192 + d] = f2b(v);
                    else {
                        u16 bv = f2b(v);
                        ((u16*)out1)[base * 128 + (d - 128)] = bv;
                        ((u16*)out2)[((size_t)(b * 16 + h) * 128 + (d - 128)) * 2048 + t] = bv;
                    }
                } else {
                    ((float*)out0)[(size_t)row * 2048 + col] = v;
                }
            }
}

// ---------------- LayerNorm(512) + k_rope broadcast ----------------
__global__ __launch_bounds__(256)
void ln_krope(const float* __restrict__ kvf, const float* __restrict__ gamma,
              const float* __restrict__ beta, const float2* __restrict__ tab,
              u16* __restrict__ kvlat, u16* __restrict__ kbuf) {
    int row = blockIdx.x, tid = threadIdx.x;
    const float* x = kvf + (size_t)row * 640;
    float v0 = x[tid], v1 = x[tid + 256];
    float s = v0 + v1, sq = v0 * v0 + v1 * v1;
#pragma unroll
    for (int off = 1; off < 64; off <<= 1) { s += __shfl_xor(s, off); sq += __shfl_xor(sq, off); }
    __shared__ float ssum[4], ssq[4];
    if ((tid & 63) == 0) { ssum[tid >> 6] = s; ssq[tid >> 6] = sq; }
    __syncthreads();
    s = ssum[0] + ssum[1] + ssum[2] + ssum[3];
    sq = ssq[0] + ssq[1] + ssq[2] + ssq[3];
    float mu = s * (1.f / 512.f);
    float var = sq * (1.f / 512.f) - mu * mu;
    float rs = rsqrtf(var + 1e-5f);
    kvlat[(size_t)row * 512 + tid] = f2b((v0 - mu) * rs * gamma[tid] + beta[tid]);
    kvlat[(size_t)row * 512 + tid + 256] = f2b((v1 - mu) * rs * gamma[tid + 256] + beta[tid + 256]);
    if (tid < 32) {
        int t = row & 2047, b = row >> 11;
        float x1 = x[512 + 2 * tid], x2 = x[512 + 2 * tid + 1];
        float2 cs = tab[t * 32 + tid];
        u16 u1 = f2b(x1 * cs.x - x2 * cs.y), u2 = f2b(x1 * cs.y + x2 * cs.x);
        for (int h = 0; h < 16; ++h) {
            size_t base = ((size_t)(b * 16 + h) * 2048 + t) * 192 + 128 + 2 * tid;
            kbuf[base] = u1; kbuf[base + 1] = u2;
        }
    }
}

// ---------------- parallel suffix scan of V -> u term written into attnb ----------------
__global__ void suff1(const u16* __restrict__ vbuf, float* __restrict__ psum) {
    int bh = blockIdx.x, c = blockIdx.y, d = threadIdx.x;   // 128 threads
    float s = 0.f;
    const u16* vp = vbuf + ((size_t)bh * 2048 + c * 128) * 128 + d;
    for (int tt = 0; tt < 128; ++tt) s += b2f(vp[(size_t)tt * 128]);
    psum[((size_t)bh * 16 + c) * 128 + d] = s;
}
__global__ void suff2(const float* __restrict__ psum, float* __restrict__ csuf) {
    int bh = blockIdx.x, d = threadIdx.x;
    float run = 0.f;
    for (int c = 15; c >= 0; --c) {
        csuf[((size_t)bh * 16 + c) * 128 + d] = run;
        run += psum[((size_t)bh * 16 + c) * 128 + d];
    }
}
__global__ void suff3(const u16* __restrict__ vbuf, const float* __restrict__ csuf,
                      u16* __restrict__ attnb) {
    int bh = blockIdx.x, c = blockIdx.y, d = threadIdx.x;
    int b = bh >> 4, h = bh & 15;
    float run = csuf[((size_t)bh * 16 + c) * 128 + d];
    for (int tt = 127; tt >= 0; --tt) {
        int t = c * 128 + tt;
        attnb[((size_t)b * 2048 + t) * 2048 + h * 128 + d] = f2b(run * 0.0625f);
        run += b2f(vbuf[((size_t)bh * 2048 + t) * 128 + d]);
    }
}

// ---------------- Z kernel: ztb[b][t][s] = 1 / sum_h exp(SCALE*q.k), bf16 ----------------
// s-grouped (2 s-tiles/block, Q reuse); dbuf K LDS (48KB -> 3 blocks/CU); counted vmcnt
__global__ __launch_bounds__(256, 3)
void z_kernel(const u16* __restrict__ qbuf, const u16* __restrict__ kbuf,
              u16* __restrict__ ztb) {
    __shared__ __align__(16) u16 Ks[2 * 12288];
    const int tid = threadIdx.x, lane = tid & 63, wave = tid >> 6;
    const int hi = lane >> 5, l31 = lane & 31;
    const int tgrp = wave & 1, sblk = wave >> 1;
    int id = blockIdx.x;            // 0..543
    int b = id & 1, p = id >> 1;    // p in [0,272)
    int tT = 0;
    for (;;) { int cnt = (tT + 2) >> 1; if (p < cnt) break; p -= cnt; ++tT; }
    const int g2 = p * 2;           // first s-tile of the group
    const int ns = ((tT + 1 - g2) >= 2) ? 2 : 1;
    const int t0 = tT * 64;
    const int rK = sblk * 32 + l31;
    const int t_loc = tgrp * 32 + l31;

    bf16x8 qA[12];
    auto QLOAD = [&](int h) {
        const u16* qp = qbuf + ((size_t)(b * 16 + h) * 2048 + t0 + t_loc) * 192 + hi * 8;
#pragma unroll
        for (int kk = 0; kk < 12; kk++) qA[kk] = *(const bf16x8*)(qp + kk * 16);
    };
    auto KSTAGE = [&](int h, int st, int bi) {
        const size_t hrow = (size_t)(b * 16 + h) * 2048;
        const int s0 = st * 64;
#pragma unroll
        for (int j2 = 0; j2 < 6; j2++) {
            int idx = (wave * 6 + j2) * 64 + lane;
            int rr2 = idx / 24, cc = idx % 24, cs = cc ^ (rr2 & 7);
            gload_lds16(kbuf + (hrow + s0 + rr2) * 192 + cs * 8, &Ks[bi * 12288 + idx * 8]);
        }
    };
    f32x16 za0, za1;
#pragma unroll
    for (int r = 0; r < 16; r++) { za0[r] = 0.f; za1[r] = 0.f; }
    auto COMPUTE = [&](f32x16& za, const u16* K) {
        f32x16 e;
#pragma unroll
        for (int r = 0; r < 16; r++) e[r] = 0.f;
        __builtin_amdgcn_s_setprio(1);
#pragma unroll
        for (int kk = 0; kk < 12; kk++) {
            int slot = (2 * kk + hi) ^ (rK & 7);
            bf16x8 kf = *(const bf16x8*)&K[rK * 192 + slot * 8];
            e = __builtin_amdgcn_mfma_f32_32x32x16_bf16(kf, qA[kk], e, 0, 0, 0);
        }
        __builtin_amdgcn_s_setprio(0);
#pragma unroll
        for (int r = 0; r < 16; r++) za[r] += __expf(e[r] * SCALE_QK);
    };

    QLOAD(0);
    KSTAGE(0, g2, 0);
    asm volatile("s_waitcnt vmcnt(0)" ::: "memory");
    __builtin_amdgcn_s_barrier();
    int kb = 0;
#pragma unroll 1
    for (int h = 0; h < 16; ++h) {
        // ---- j = 0 (s-tile g2) ----
        if (ns == 2)      KSTAGE(h, g2 + 1, kb ^ 1);
        else if (h < 15)  KSTAGE(h + 1, g2, kb ^ 1);
        if (ns == 2 || h < 15) {
            if (h > 0) { asm volatile("s_waitcnt vmcnt(18)" ::: "memory"); }
            else       { asm volatile("s_waitcnt vmcnt(6)"  ::: "memory"); }
        } else {
            asm volatile("s_waitcnt vmcnt(12)" ::: "memory");
        }
        __builtin_amdgcn_s_barrier();
        __builtin_amdgcn_sched_barrier(0);
        COMPUTE(za0, &Ks[kb * 12288]);
        __builtin_amdgcn_s_barrier();
        if (ns == 1 && h < 15) QLOAD(h + 1);
        kb ^= 1;
        // ---- j = 1 (s-tile g2+1) ----
        if (ns == 2) {
            if (h < 15) {
                KSTAGE(h + 1, g2, kb ^ 1);
                asm volatile("s_waitcnt vmcnt(6)" ::: "memory");
            } else {
                asm volatile("s_waitcnt vmcnt(0)" ::: "memory");
            }
            __builtin_amdgcn_s_barrier();
            __builtin_amdgcn_sched_barrier(0);
            COMPUTE(za1, &Ks[kb * 12288]);
            __builtin_amdgcn_s_barrier();
            if (h < 15) QLOAD(h + 1);
            kb ^= 1;
        }
    }
    // write 1/Z to [b][t][s] layout: lane's 16 values = 4 s-contiguous groups of 4
    const size_t trow = ((size_t)b * 2048 + t0 + t_loc) * 2048;
#pragma unroll
    for (int g3 = 0; g3 < 4; g3++) {
        u16x4 zo;
#pragma unroll
        for (int j = 0; j < 4; j++) zo[j] = f2b(__fdividef(1.f, za0[g3 * 4 + j]));
        *(u16x4*)&ztb[trow + g2 * 64 + sblk * 32 + 4 * hi + 8 * g3] = zo;
    }
    if (ns == 2) {
#pragma unroll
        for (int g3 = 0; g3 < 4; g3++) {
            u16x4 zo;
#pragma unroll
            for (int j = 0; j < 4; j++) zo[j] = f2b(__fdividef(1.f, za1[g3 * 4 + j]));
            *(u16x4*)&ztb[trow + (g2 + 1) * 64 + sblk * 32 + 4 * hi + 8 * g3] = zo;
        }
    }
}

// ---------------- PV kernel: attnb += sum_{s<=t} exp(x)*rz * v ----------------
// swapped 32x32 QK^T; P in registers; K/V dbuf (80KB); Z direct-from-global prefetch
__global__ __launch_bounds__(512, 1)
void attn_pv(const u16* __restrict__ qbuf, const u16* __restrict__ kbuf,
             const u16* __restrict__ vtbuf, const u16* __restrict__ ztb,
             u16* __restrict__ attnb) {
    __shared__ __align__(16) u16 lds[40960];   // K 2x12288 | V 2x8192 = 80KB
    u16* Ks = lds;
    u16* Vt = lds + 24576;
    const int tid = threadIdx.x, lane = tid & 63, wave = tid >> 6;
    const int hi = lane >> 5, l31 = lane & 31;
    const int tgrp = wave & 3, sblk = wave >> 2;
    int id = blockIdx.x;             // 0..255
    int xcd = id & 7, j2 = id >> 3;
    int pr = j2 & 7, g = j2 >> 3;
    int bh = xcd * 4 + g;
    const int b = bh >> 4, h = bh & 15;
    const size_t kvrow = (size_t)bh * 2048;
    const int rK = sblk * 32 + l31;
    const int t_loc = tgrp * 32 + l31;

    for (int part = 0; part < 2; ++part) {
        const int T = part ? (15 - pr) : pr;
        const int t0p = T * 128, nst = 2 * T + 2;
        const int tg = t0p + t_loc;
        const u16* zrow = ztb + ((size_t)b * 2048 + tg) * 2048;   // lane's t-row
        const int zbase0 = sblk * 32 + 4 * hi;

        bf16x8 qf[12];
        {
            const u16* qp = qbuf + (kvrow + tg) * 192 + hi * 8;
#pragma unroll
            for (int kk = 0; kk < 12; kk++) qf[kk] = *(const bf16x8*)(qp + kk * 16);
        }
        f32x16 o[4];
#pragma unroll
        for (int db = 0; db < 4; db++)
#pragma unroll
            for (int r = 0; r < 16; r++) o[db][r] = 0.f;

        auto STAGE = [&](int st, int bi) {   // 5 gload_lds per wave
            const int s0 = st * 64;
#pragma unroll
            for (int j = 0; j < 3; j++) {      // K: 24KB
                int idx = (wave * 3 + j) * 64 + lane;
                int rr2 = idx / 24, cc = idx % 24, cs = cc ^ (rr2 & 7);
                gload_lds16(kbuf + (kvrow + s0 + rr2) * 192 + cs * 8, &Ks[bi * 12288 + idx * 8]);
            }
#pragma unroll
            for (int j = 0; j < 2; j++) {      // V^T: 16KB
                int idx = (wave * 2 + j) * 64 + lane;
                int d = idx >> 3, cc = idx & 7, cs = cc ^ (d & 7);
                gload_lds16(vtbuf + ((size_t)bh * 128 + d) * 2048 + s0 + cs * 8, &Vt[bi * 8192 + idx * 8]);
            }
        };
        u16x4 zc0, zc1, zc2, zc3, zn0, zn1, zn2, zn3;
        auto ZLOAD = [&](int st, u16x4& a, u16x4& bb, u16x4& c, u16x4& d) {
            int base = st * 64 + zbase0;
            a  = *(const u16x4*)(zrow + base);
            bb = *(const u16x4*)(zrow + base + 8);
            c  = *(const u16x4*)(zrow + base + 16);
            d  = *(const u16x4*)(zrow + base + 24);
        };
        // prologue: 9 vmem ops (5 stage + 4 z)
        STAGE(0, 0);
        ZLOAD(0, zc0, zc1, zc2, zc3);
        for (int st = 0; st < nst; ++st) {
            int cur = st & 1;
            if (st + 1 < nst) {
                STAGE(st + 1, cur ^ 1);
                ZLOAD(st + 1, zn0, zn1, zn2, zn3);
                // 9 newer ops in flight; wait for iter-st's 9 (FIFO)
                asm volatile("s_waitcnt vmcnt(9)" ::: "memory");
            } else {
                asm volatile("s_waitcnt vmcnt(0)" ::: "memory");
            }
            __builtin_amdgcn_s_barrier();
            __builtin_amdgcn_sched_barrier(0);
            const u16* Kc = &Ks[cur * 12288];
            const u16* Vc = &Vt[cur * 8192];
            // QK^T swapped: S^T[s][t]
            f32x16 sacc;
#pragma unroll
            for (int r = 0; r < 16; r++) sacc[r] = 0.f;
            __builtin_amdgcn_s_setprio(1);
#pragma unroll
            for (int kk = 0; kk < 12; kk++) {
                int slot = (2 * kk + hi) ^ (rK & 7);
                bf16x8 kf = *(const bf16x8*)&Kc[rK * 192 + slot * 8];
                sacc = __builtin_amdgcn_mfma_f32_32x32x16_bf16(kf, qf[kk], sacc, 0, 0, 0);
            }
            __builtin_amdgcn_s_setprio(0);
            // softmax: w = exp * rz (causal), rz from prefetched regs
            const int s0g = st * 64 + sblk * 32;
            float w[16];
#define SMG(g3, zcv)                                                        \
_Pragma("unroll")                                                           \
            for (int j = 0; j < 4; j++) {                                   \
                int r = g3 * 4 + j;                                         \
                int spat = j + 8 * g3 + 4 * hi;                             \
                w[r] = (s0g + spat <= tg)                                   \
                     ? __expf(sacc[r] * SCALE_QK) * b2f(zcv[j]) : 0.f;      \
            }
            SMG(0, zc0) SMG(1, zc1) SMG(2, zc2) SMG(3, zc3)
#undef SMG
            // pack to PV A-frags (T12): word m of frag holds s_local {hi*8+2m, hi*8+2m+1}
            unsigned pw0 = pk2(w[0], w[1]), pw1 = pk2(w[2], w[3]);
            unsigned pw2 = pk2(w[4], w[5]), pw3 = pk2(w[6], w[7]);
            unsigned pw4 = pk2(w[8], w[9]), pw5 = pk2(w[10], w[11]);
            unsigned pw6 = pk2(w[12], w[13]), pw7 = pk2(w[14], w[15]);
            unsigned a0 = pw0, a1 = pw1, a2 = pw4, a3 = pw5;
            asm volatile("v_permlane32_swap_b32 %0, %1" : "+v"(a0), "+v"(pw2));
            asm volatile("v_permlane32_swap_b32 %0, %1" : "+v"(a1), "+v"(pw3));
            asm volatile("v_permlane32_swap_b32 %0, %1" : "+v"(a2), "+v"(pw6));
            asm volatile("v_permlane32_swap_b32 %0, %1" : "+v"(a3), "+v"(pw7));
            union PU { unsigned u[4]; bf16x8 v; } p0, p1;
            p0.u[0] = a0;  p0.u[1] = a1;  p0.u[2] = pw2; p0.u[3] = pw3;   // s_local 0..15
            p1.u[0] = a2;  p1.u[1] = a3;  p1.u[2] = pw6; p1.u[3] = pw7;   // s_local 16..31
            // PV: o[t][d] += P[t][s] V[s][d], s within THIS wave's sblk half
            __builtin_amdgcn_s_setprio(1);
#pragma unroll
            for (int db = 0; db < 4; db++) {
                int dv = db * 32 + l31;
#pragma unroll
                for (int ks = 0; ks < 2; ks++) {
                    int slot = (sblk * 4 + 2 * ks + hi) ^ (dv & 7);
                    bf16x8 vb = *(const bf16x8*)&Vc[dv * 64 + slot * 8];
                    o[db] = __builtin_amdgcn_mfma_f32_32x32x16_bf16(ks ? p1.v : p0.v, vb, o[db], 0, 0, 0);
                }
            }
            __builtin_amdgcn_s_setprio(0);
            __builtin_amdgcn_s_barrier();
            if (st + 1 < nst) { zc0 = zn0; zc1 = zn1; zc2 = zn2; zc3 = zn3; }
        }
        // epilogue: cross-wave (sblk0 + sblk1) reduce via LDS, add u term, write
        __syncthreads();
        float* red = (float*)lds;   // [128t][128d] f32 = 64KB (fits in 80KB)
        if (sblk == 0) {
#pragma unroll
            for (int db = 0; db < 4; db++)
#pragma unroll
                for (int r = 0; r < 16; r++) {
                    int trow = (r & 3) + 8 * (r >> 2) + 4 * hi;
                    red[(tgrp * 32 + trow) * 128 + db * 32 + l31] = o[db][r];
                }
        }
        __syncthreads();
        if (sblk == 1) {
#pragma unroll
            for (int db = 0; db < 4; db++)
#pragma unroll
                for (int r = 0; r < 16; r++) {
                    int trow = (r & 3) + 8 * (r >> 2) + 4 * hi;
                    float val = o[db][r] + red[(tgrp * 32 + trow) * 128 + db * 32 + l31];
                    size_t oi = ((size_t)b * 2048 + t0p + tgrp * 32 + trow) * 2048 + h * 128 + db * 32 + l31;
                    attnb[oi] = f2b(val + b2f(attnb[oi]));
                }
        }
        __syncthreads();   // red/lds dead before next part's STAGE
    }
}

// ---------------- launch ----------------
extern "C" void kernel_launch(void* const* d_in, const int* in_sizes, int n_in,
                              void* d_out, int out_size, void* d_ws, size_t ws_size,
                              hipStream_t stream) {
    (void)in_sizes; (void)n_in; (void)out_size;
    const float* hidden = (const float*)d_in[0];
    const float* freqs  = (const float*)d_in[1];
    const float* Wq     = (const float*)d_in[3];
    const float* Wkva   = (const float*)d_in[4];
    const float* gamma  = (const float*)d_in[5];
    const float* beta   = (const float*)d_in[6];
    const float* Wkvb   = (const float*)d_in[7];
    const float* Wout   = (const float*)d_in[8];
    float* outp = (float*)d_out;

    char* ws = (char*)d_ws;
    size_t off = 0;
    auto alloc = [&](size_t bytes) -> void* {
        void* p = ws + off; off += (bytes + 255) & ~(size_t)255; return p;
    };
    u16*   hid_b = (u16*)alloc((size_t)MROWS * HID * 2);
    u16*   WqT   = (u16*)alloc((size_t)3072 * 2048 * 2);
    u16*   WkvaT = (u16*)alloc((size_t)640 * 2048 * 2);
    u16*   WkvbT = (u16*)alloc((size_t)4096 * 512 * 2);
    u16*   WoutT = (u16*)alloc((size_t)2048 * 2048 * 2);
    u16*   qbuf  = (u16*)alloc((size_t)BATCH * NHEAD * TSEQ * QK * 2);
    float* kvf   = (float*)alloc((size_t)MROWS * 640 * 4);
    u16*   kvlat = (u16*)alloc((size_t)MROWS * 512 * 2);
    u16*   kbuf  = (u16*)alloc((size_t)BATCH * NHEAD * TSEQ * QK * 2);
    u16*   vbuf  = (u16*)alloc((size_t)BATCH * NHEAD * TSEQ * VD * 2);
    u16*   attnb = (u16*)alloc((size_t)MROWS * 2048 * 2);
    float2* ropetab = (float2*)alloc((size_t)2048 * 32 * 8);
    float* psum  = (float*)alloc((size_t)32 * 16 * 128 * 4);
    float* csuf  = (float*)alloc((size_t)32 * 16 * 128 * 4);
    if (off > ws_size) return;
    // overlays (dead regions by the time they're written):
    u16* ztb   = WqT;     // 16.78 MB spanning WqT+WkvaT+part of WkvbT, free after gemm<0>/<2>
    u16* vtbuf = hid_b;   // 16.78 MB, free after gemm<0>/<1>

    cvt_bf16x8<<<4096, 256, 0, stream>>>(hidden, hid_b, MROWS * HID / 8);
    rope_tab_k<<<256, 256, 0, stream>>>(freqs, ropetab);
    dim3 tb(32, 8);
    transpose_cvt<<<dim3(96, 64), tb, 0, stream>>>(Wq, WqT, 2048, 3072, 3072);
    transpose_cvt<<<dim3(20, 64), tb, 0, stream>>>(Wkva, WkvaT, 2048, 576, 640);
    transpose_cvt<<<dim3(128, 16), tb, 0, stream>>>(Wkvb, WkvbT, 512, 4096, 4096);
    transpose_cvt<<<dim3(64, 64), tb, 0, stream>>>(Wout, WoutT, 2048, 2048, 2048);

    gemm_bt<1><<<dim3(32, 5), 256, 0, stream>>>(hid_b, WkvaT, 2048, kvf, nullptr, nullptr, nullptr);
    gemm_bt<0><<<dim3(32, 24), 256, 0, stream>>>(hid_b, WqT, 2048, qbuf, nullptr, nullptr, ropetab);
    ln_krope<<<MROWS, 256, 0, stream>>>(kvf, gamma, beta, ropetab, kvlat, kbuf);
    gemm_bt<2><<<dim3(32, 32), 256, 0, stream>>>(kvlat, WkvbT, 512, kbuf, vbuf, vtbuf, nullptr);

    suff1<<<dim3(32, 16), 128, 0, stream>>>(vbuf, psum);
    suff2<<<32, 128, 0, stream>>>(psum, csuf);
    suff3<<<dim3(32, 16), 128, 0, stream>>>(vbuf, csuf, attnb);

    z_kernel<<<544, 256, 0, stream>>>(qbuf, kbuf, ztb);
    attn_pv<<<256, 512, 0, stream>>>(qbuf, kbuf, vtbuf, ztb, attnb);

    gemm_bt<3><<<dim3(32, 16), 256, 0, stream>>>(attnb, WoutT, 2048, outp, nullptr, nullptr, nullptr);
}